// Round 14
// baseline (162.477 us; speedup 1.0000x reference)
//
#include <hip/hip_runtime.h>
#include <stdint.h>

#define D_DIM   512
#define BM      64
#define THREADS 256            // 4 waves; each wave owns 128 N-cols (nt=8)
#define NBLOCKS 2048           // 131072 / 64
#define RING    6
#define SLOT    8192           // bytes: fp32 slice [64 rows][32 cols]

typedef __attribute__((ext_vector_type(8))) __bf16 bf16x8;
typedef __attribute__((ext_vector_type(4))) float  f32x4;

__device__ __forceinline__ unsigned short f32_to_bf16_rne(float f) {
    uint32_t u = __builtin_bit_cast(uint32_t, f);
    u += 0x7FFFu + ((u >> 16) & 1u);
    return (unsigned short)(u >> 16);
}

// Repack L (fp32 row-major [K=512][N=512]) into bf16 fragment order:
// flat ushort idx = ((ks*32 + ntg)*64 + lane)*8 + e  holds L[k][n],
//   n = ntg*16 + (lane&15),  k = ks*32 + (lane>>4)*8 + e.
__global__ void prep_lt(const float* __restrict__ L, unsigned short* __restrict__ Ltf) {
    int o = blockIdx.x * 256 + threadIdx.x;
    #pragma unroll
    for (int i = 0; i < 4; ++i) {
        int idx  = o + i * 65536;
        int e    = idx & 7;
        int l    = (idx >> 3) & 63;
        int tile = idx >> 9;
        int ntg  = tile & 31;
        int ks   = tile >> 5;
        int n    = ntg * 16 + (l & 15);
        int k    = ks * 32 + (l >> 4) * 8 + e;
        Ltf[idx] = f32_to_bf16_rne(L[k * 512 + n]);
    }
}

__global__ __launch_bounds__(THREADS, 2)
void psd_main(const float* __restrict__ x, const unsigned short* __restrict__ Ltf,
              const float* __restrict__ b, const float* __restrict__ c,
              float* __restrict__ out) {
    // 6-slot fp32 ring; stored 16B-unit u at row r holds logical u^(r&7).
    __shared__ __align__(16) float ring[RING * BM * 32];   // 48 KiB
    __shared__ __align__(16) float bsh[D_DIM];             // 2 KiB
    __shared__ unsigned staged[16];
    __shared__ unsigned consumed[16];
    __shared__ float wpart[4][BM];
    __shared__ float bpart[BM];

    const int t    = threadIdx.x;
    const int w    = t >> 6;
    const int lane = t & 63;
    const int g    = lane >> 4;
    const int ln   = lane & 15;
    const int r8   = lane >> 3;
    const int u8   = lane & 7;

    char* ringB = (char*)&ring[0];
    char* bshB  = (char*)&bsh[0];
    const char* xB = (const char*)x + (size_t)blockIdx.x * (BM * 2048);
    const unsigned short* LtW = Ltf + (size_t)w * 4096 + (size_t)lane * 8;

    volatile unsigned* vst = staged;
    volatile unsigned* vco = consumed;
    if (t < 16) { staged[t] = 0; consumed[t] = 0; }
    __syncthreads();   // only barrier before the epilogue

    f32x4 acc[4][8];
    #pragma unroll
    for (int m = 0; m < 4; ++m)
        #pragma unroll
        for (int nt = 0; nt < 8; ++nt)
            acc[m][nt] = (f32x4){0.f, 0.f, 0.f, 0.f};
    float bacc = 0.f;

    // Stage own quarter (rows w*16..+15) of fp32 slice K into ring offset SOFF.
#define STAGE(K, SOFF)                                                                   \
    {                                                                                    \
        char* ldsw = ringB + (SOFF) + w * 2048;                                          \
        _Pragma("unroll")                                                                \
        for (int j = 0; j < 2; ++j) {                                                    \
            const char* gsrc = xB + (size_t)(w * 16 + j * 8 + r8) * 2048 + (K) * 128     \
                             + ((u8 ^ r8) << 4);                                         \
            __builtin_amdgcn_global_load_lds(                                            \
                (const __attribute__((address_space(1))) void*)gsrc,                     \
                (__attribute__((address_space(3))) void*)(ldsw + j * 1024), 16, 0, 0);   \
        }                                                                                \
    }

#define LOADB(DST, Q)                                                                    \
    {                                                                                    \
        _Pragma("unroll")                                                                \
        for (int i = 0; i < 8; ++i)                                                      \
            (DST)[i] = *(const bf16x8*)(LtW + (size_t)(Q) * 16384 + i * 512);            \
    }

#define COMPUTE(RBOFF)                                                                   \
    {                                                                                    \
        __builtin_amdgcn_s_setprio(1);                                                   \
        _Pragma("unroll")                                                                \
        for (int m = 0; m < 4; ++m) {                                                    \
            const int row = m * 16 + ln;                                                 \
            const char* rp = ringB + (RBOFF) + row * 128;                                \
            f32x4 f0 = *(const f32x4*)(rp + (((g * 2    ) ^ (ln & 7)) << 4));            \
            f32x4 f1 = *(const f32x4*)(rp + (((g * 2 + 1) ^ (ln & 7)) << 4));            \
            bf16x8 a;                                                                    \
            a[0] = (__bf16)f0[0]; a[1] = (__bf16)f0[1];                                  \
            a[2] = (__bf16)f0[2]; a[3] = (__bf16)f0[3];                                  \
            a[4] = (__bf16)f1[0]; a[5] = (__bf16)f1[1];                                  \
            a[6] = (__bf16)f1[2]; a[7] = (__bf16)f1[3];                                  \
            _Pragma("unroll")                                                            \
            for (int nt = 0; nt < 8; ++nt)                                               \
                acc[m][nt] = __builtin_amdgcn_mfma_f32_16x16x32_bf16(a, bcur[nt], acc[m][nt], 0, 0, 0); \
        }                                                                                \
        __builtin_amdgcn_s_setprio(0);                                                   \
    }

#define XB(RBOFF, BOFF)                                                                  \
    {                                                                                    \
        const int row = t >> 2;                                                          \
        _Pragma("unroll")                                                                \
        for (int i = 0; i < 2; ++i) {                                                    \
            const int unit = (t & 3) * 2 + i;                                            \
            f32x4 xv = *(const f32x4*)(ringB + (RBOFF) + row * 128 + ((unit ^ (row & 7)) << 4)); \
            f32x4 bv = *(const f32x4*)(bshB + (BOFF) + unit * 16);                       \
            bacc += xv[0] * bv[0] + xv[1] * bv[1] + xv[2] * bv[2] + xv[3] * bv[3];       \
        }                                                                                \
    }

#define BUMP(ARR, IDX) if (lane == 0) atomicAdd((unsigned*)&(ARR)[(IDX)], 1u);
#define SWAPB() { _Pragma("unroll") for (int i = 0; i < 8; ++i) bcur[i] = bnxt[i]; }

    // ---- prologue: b (oldest), bfr(0), stages 0..4 ----
    if (lane < 32) {
        const char* gsrc = (const char*)b + (size_t)(w * 512 + lane * 16);
        __builtin_amdgcn_global_load_lds(
            (const __attribute__((address_space(1))) void*)gsrc,
            (__attribute__((address_space(3))) void*)(bshB + w * 512 + lane * 16), 16, 0, 0);
    }
    bf16x8 bcur[8], bnxt[8];
    LOADB(bcur, 0)
    STAGE(0, 0) STAGE(1, 8192) STAGE(2, 16384) STAGE(3, 24576) STAGE(4, 32768)

    // ---- iter 0 ----
    STAGE(5, 40960)
    LOADB(bnxt, 1)
    asm volatile("s_waitcnt vmcnt(10)" ::: "memory");
    BUMP(staged, 0) BUMP(staged, 1) BUMP(staged, 2) BUMP(staged, 3) BUMP(staged, 4)
    while (vst[0] < 4u) ;
    COMPUTE(0)
    XB(0, 0)
    asm volatile("s_waitcnt lgkmcnt(0)" ::: "memory");
    BUMP(consumed, 0)
    SWAPB()

    // ---- main loop: q = 1..10 ----
    {
        int rbOff = 8192;        // slot q%6
        int stOff = 0;           // slot (q+5)%6
        int boff  = 128;
        const unsigned short* Lp = LtW + 2 * 16384;   // bfr(q+1)

        #pragma unroll 1
        for (int q = 1; q <= 10; ++q) {
            while (vco[q - 1] < 4u) ;
            STAGE(q + 5, stOff)
            #pragma unroll
            for (int i = 0; i < 8; ++i)
                bnxt[i] = *(const bf16x8*)(Lp + i * 512);
            asm volatile("s_waitcnt vmcnt(10)" ::: "memory");
            BUMP(staged, q + 4)
            while (vst[q] < 4u) ;
            COMPUTE(rbOff)
            XB(rbOff, boff)
            asm volatile("s_waitcnt lgkmcnt(0)" ::: "memory");
            BUMP(consumed, q)
            SWAPB()
            rbOff += 8192; if (rbOff == RING * SLOT) rbOff = 0;
            stOff += 8192; if (stOff == RING * SLOT) stOff = 0;
            boff  += 128;
            Lp    += 16384;
        }
    }

    // ---- tail: q = 11..15 (no staging; slots 5,0,1,2,3) ----
#define TAIL(Q, RBOFF, HASB, VM)                                                         \
    {                                                                                    \
        if (HASB) LOADB(bnxt, (Q) + 1)                                                   \
        asm volatile("s_waitcnt vmcnt(" #VM ")" ::: "memory");                           \
        while (vst[(Q)] < 4u) ;                                                          \
        COMPUTE(RBOFF)                                                                   \
        XB(RBOFF, (Q) * 128)                                                             \
        SWAPB()                                                                          \
    }
    if (lane == 0) atomicAdd((unsigned*)&staged[15], 1u);   // confirmed by vmcnt below
    asm volatile("s_waitcnt vmcnt(8)" ::: "memory");        // retires bfr(11)+stage(15)
    while (vst[11] < 4u) ;
    COMPUTE(40960)
    XB(40960, 11 * 128)
    LOADB(bnxt, 12)   // hmm: keep simple -- reload pattern below
    SWAPB()
    TAIL(12, 0,     1, 8)
    TAIL(13, 8192,  1, 8)
    TAIL(14, 16384, 1, 8)
    TAIL(15, 24576, 0, 0)
#undef TAIL
#undef STAGE
#undef LOADB
#undef COMPUTE
#undef XB
#undef BUMP
#undef SWAPB

    // rowsum of squares; C/D layout: col = lane&15, row = 4*(lane>>4) + reg
    __syncthreads();
    #pragma unroll
    for (int m = 0; m < 4; ++m) {
        #pragma unroll
        for (int r = 0; r < 4; ++r) {
            float s = 0.f;
            #pragma unroll
            for (int nt = 0; nt < 8; ++nt) { float vv = acc[m][nt][r]; s += vv * vv; }
            s += __shfl_xor(s, 1);
            s += __shfl_xor(s, 2);
            s += __shfl_xor(s, 4);
            s += __shfl_xor(s, 8);
            if (ln == 0) wpart[w][m * 16 + g * 4 + r] = s;
        }
    }
    {
        float s = bacc;
        s += __shfl_xor(s, 1);
        s += __shfl_xor(s, 2);
        if ((lane & 3) == 0) bpart[t >> 2] = s;
    }
    __syncthreads();

    if (t < BM) {
        float y = c[0] + bpart[t]
                + wpart[0][t] + wpart[1][t] + wpart[2][t] + wpart[3][t];
        out[(size_t)blockIdx.x * BM + t] = y;
    }
}

extern "C" void kernel_launch(void* const* d_in, const int* in_sizes, int n_in,
                              void* d_out, int out_size, void* d_ws, size_t ws_size,
                              hipStream_t stream) {
    const float* x = (const float*)d_in[0];
    const float* L = (const float*)d_in[1];
    const float* b = (const float*)d_in[2];
    const float* c = (const float*)d_in[3];
    float* out = (float*)d_out;
    unsigned short* Ltf = (unsigned short*)d_ws;   // 512 KiB

    prep_lt<<<256, 256, 0, stream>>>(L, Ltf);
    psd_main<<<NBLOCKS, THREADS, 0, stream>>>(x, Ltf, b, c, out);
}

// Round 15
// 102.915 us; speedup vs baseline: 1.5788x; 1.5788x over previous
//
#include <hip/hip_runtime.h>
#include <stdint.h>

#define D_DIM   512
#define BM      64
#define THREADS 256            // 4 waves; wave owns 128 N-cols in 2 groups of 64
#define NBLOCKS 2048           // 131072 / 64

typedef __attribute__((ext_vector_type(8))) __bf16 bf16x8;
typedef __attribute__((ext_vector_type(4))) float  f32x4;

__device__ __forceinline__ unsigned short f32_to_bf16_rne(float f) {
    uint32_t u = __builtin_bit_cast(uint32_t, f);
    u += 0x7FFFu + ((u >> 16) & 1u);
    return (unsigned short)(u >> 16);
}

// Repack L (fp32 row-major [K=512][N=512]) into bf16 fragment order:
// flat ushort idx = ((ks*32 + ntg)*64 + lane)*8 + e  holds L[k][n],
//   n = ntg*16 + (lane&15),  k = ks*32 + (lane>>4)*8 + e.
__global__ void prep_lt(const float* __restrict__ L, unsigned short* __restrict__ Ltf) {
    int o = blockIdx.x * 256 + threadIdx.x;
    #pragma unroll
    for (int i = 0; i < 4; ++i) {
        int idx  = o + i * 65536;
        int e    = idx & 7;
        int l    = (idx >> 3) & 63;
        int tile = idx >> 9;
        int ntg  = tile & 31;
        int ks   = tile >> 5;
        int n    = ntg * 16 + (l & 15);
        int k    = ks * 32 + (l >> 4) * 8 + e;
        Ltf[idx] = f32_to_bf16_rne(L[k * 512 + n]);
    }
}

__global__ __launch_bounds__(THREADS, 2)
void psd_main(const float* __restrict__ x, const unsigned short* __restrict__ Ltf,
              const float* __restrict__ b, const float* __restrict__ c,
              float* __restrict__ out) {
    // whole x-tile as bf16: [64 rows][512 cols], row = 1 KiB = 64 16B-units;
    // stored unit su at row r holds logical unit su ^ (r&7) (involution).
    __shared__ __align__(16) unsigned short xs[BM * D_DIM];   // 64 KiB
    __shared__ __align__(16) float bsh[D_DIM];                // 2 KiB (fp32 b)
    __shared__ float wpart[4][BM];
    __shared__ float bpart[BM];

    const int t    = threadIdx.x;
    const int w    = t >> 6;
    const int lane = t & 63;
    const int g    = lane >> 4;
    const int ln   = lane & 15;

    char* xsB  = (char*)&xs[0];
    char* bshB = (char*)&bsh[0];

    // ---- prologue: b -> LDS; x tile fp32 -> bf16 LDS (2 batches of 16 f4) ----
    if (t < 128) {
        __builtin_amdgcn_global_load_lds(
            (const __attribute__((address_space(1))) void*)((const char*)b + (size_t)t * 16),
            (__attribute__((address_space(3))) void*)(bshB + t * 16), 16, 0, 0);
    }
    {
        const float4* xg = (const float4*)(x + (size_t)blockIdx.x * BM * D_DIM);
        float4 v0[16], v1[16];
        #pragma unroll
        for (int i = 0; i < 16; ++i) v0[i] = xg[i * THREADS + t];
        #pragma unroll
        for (int i = 0; i < 16; ++i) v1[i] = xg[(16 + i) * THREADS + t];
        asm volatile("s_waitcnt vmcnt(16)" ::: "memory");   // b + v0 retired; v1 flying
        #pragma unroll
        for (int i = 0; i < 16; ++i) {
            int f = i * THREADS + t, row = f >> 7, col4 = f & 127;
            ushort4 h;
            h.x = f32_to_bf16_rne(v0[i].x); h.y = f32_to_bf16_rne(v0[i].y);
            h.z = f32_to_bf16_rne(v0[i].z); h.w = f32_to_bf16_rne(v0[i].w);
            *(ushort4*)(xsB + row * 1024 + (((col4 >> 1) ^ (row & 7)) << 4) + (col4 & 1) * 8) = h;
        }
        asm volatile("s_waitcnt vmcnt(0)" ::: "memory");
        #pragma unroll
        for (int i = 0; i < 16; ++i) {
            int f = (16 + i) * THREADS + t, row = f >> 7, col4 = f & 127;
            ushort4 h;
            h.x = f32_to_bf16_rne(v1[i].x); h.y = f32_to_bf16_rne(v1[i].y);
            h.z = f32_to_bf16_rne(v1[i].z); h.w = f32_to_bf16_rne(v1[i].w);
            *(ushort4*)(xsB + row * 1024 + (((col4 >> 1) ^ (row & 7)) << 4) + (col4 & 1) * 8) = h;
        }
    }
    __syncthreads();   // xs + bsh ready; NO more barriers until epilogue

    float rsum[4][4];
    #pragma unroll
    for (int m = 0; m < 4; ++m)
        #pragma unroll
        for (int r = 0; r < 4; ++r) rsum[m][r] = 0.f;

    // Load one b-frag set (4 n-tiles x K=32) at k-slice KK from group base LGP.
#define LOADBSET(DST, LGP, KK)                                                           \
    {                                                                                    \
        _Pragma("unroll")                                                                \
        for (int nt = 0; nt < 4; ++nt)                                                   \
            (DST)[nt] = *(const bf16x8*)((LGP) + (size_t)(KK) * 16384 + nt * 512);       \
    }

    // One K=32 step: 4 a-frags (bf16, ds_read_b128, swizzled) x b-set BS -> 16 MFMA.
#define ASTEP(K4, BS)                                                                    \
    {                                                                                    \
        _Pragma("unroll")                                                                \
        for (int m = 0; m < 4; ++m) {                                                    \
            const int row = m * 16 + ln;                                                 \
            bf16x8 a = *(const bf16x8*)(xsB + row * 1024 + ((((K4) + g) ^ (row & 7)) << 4)); \
            _Pragma("unroll")                                                            \
            for (int nt = 0; nt < 4; ++nt)                                               \
                acc[m][nt] = __builtin_amdgcn_mfma_f32_16x16x32_bf16(a, (BS)[nt], acc[m][nt], 0, 0, 0); \
        }                                                                                \
    }

    // One 64-col group: 16 K-steps, 4 rotating b-sets (3-deep prefetch), then
    // square-accumulate into rsum and free acc.
#define GROUP(LGP)                                                                       \
    {                                                                                    \
        f32x4 acc[4][4];                                                                 \
        _Pragma("unroll")                                                                \
        for (int m = 0; m < 4; ++m)                                                      \
            _Pragma("unroll")                                                            \
            for (int nt = 0; nt < 4; ++nt) acc[m][nt] = (f32x4){0.f, 0.f, 0.f, 0.f};     \
        bf16x8 bs0[4], bs1[4], bs2[4], bs3[4];                                           \
        LOADBSET(bs0, (LGP), 0)                                                          \
        LOADBSET(bs1, (LGP), 1)                                                          \
        LOADBSET(bs2, (LGP), 2)                                                          \
        int k4 = 0;                                                                      \
        const unsigned short* Lpre = (LGP) + 3 * 16384;                                  \
        _Pragma("unroll 1")                                                              \
        for (int kb = 0; kb < 16; kb += 4) {                                             \
            LOADBSET(bs3, Lpre, 0)                                                       \
            ASTEP(k4, bs0)                                                               \
            if (kb < 12) LOADBSET(bs0, Lpre, 1)                                          \
            ASTEP(k4 + 4, bs1)                                                           \
            if (kb < 12) LOADBSET(bs1, Lpre, 2)                                          \
            ASTEP(k4 + 8, bs2)                                                           \
            if (kb < 12) LOADBSET(bs2, Lpre, 3)                                          \
            ASTEP(k4 + 12, bs3)                                                          \
            k4 += 16;                                                                    \
            Lpre += 4 * 16384;                                                           \
        }                                                                                \
        _Pragma("unroll")                                                                \
        for (int m = 0; m < 4; ++m)                                                      \
            _Pragma("unroll")                                                            \
            for (int r = 0; r < 4; ++r) {                                                \
                float s = 0.f;                                                           \
                _Pragma("unroll")                                                        \
                for (int nt = 0; nt < 4; ++nt) { float vv = acc[m][nt][r]; s += vv * vv; } \
                rsum[m][r] += s;                                                         \
            }                                                                            \
    }

    // wave w: group A = ntg w*8..+3 (cols w*128..+64), group B = +4..7
    const unsigned short* LgA = Ltf + ((size_t)(w * 8) * 64 + lane) * 8;
    GROUP(LgA)
    GROUP(LgA + 2048)

#undef GROUP
#undef ASTEP
#undef LOADBSET

    // rowsum reduce over the 16 cols (ln lanes); C/D: col=lane&15, row=4*g+r
    #pragma unroll
    for (int m = 0; m < 4; ++m) {
        #pragma unroll
        for (int r = 0; r < 4; ++r) {
            float s = rsum[m][r];
            s += __shfl_xor(s, 1);
            s += __shfl_xor(s, 2);
            s += __shfl_xor(s, 4);
            s += __shfl_xor(s, 8);
            if (ln == 0) wpart[w][m * 16 + g * 4 + r] = s;
        }
    }

    // x.b from bf16 xs + fp32 bsh: thread covers row t>>2, 16 units (128 cols)
    {
        const int row = t >> 2;
        const int cb  = t & 3;
        float s = 0.f;
        #pragma unroll
        for (int i = 0; i < 16; ++i) {
            const int lu = cb * 16 + i;
            bf16x8 xv = *(const bf16x8*)(xsB + row * 1024 + ((lu ^ (row & 7)) << 4));
            f32x4 b0 = *(const f32x4*)(bshB + lu * 32);
            f32x4 b1 = *(const f32x4*)(bshB + lu * 32 + 16);
            s += (float)xv[0] * b0[0] + (float)xv[1] * b0[1]
               + (float)xv[2] * b0[2] + (float)xv[3] * b0[3]
               + (float)xv[4] * b1[0] + (float)xv[5] * b1[1]
               + (float)xv[6] * b1[2] + (float)xv[7] * b1[3];
        }
        s += __shfl_xor(s, 1);
        s += __shfl_xor(s, 2);
        if ((lane & 3) == 0) bpart[row] = s;
    }
    __syncthreads();

    if (t < BM) {
        float y = c[0] + bpart[t]
                + wpart[0][t] + wpart[1][t] + wpart[2][t] + wpart[3][t];
        out[(size_t)blockIdx.x * BM + t] = y;
    }
}

extern "C" void kernel_launch(void* const* d_in, const int* in_sizes, int n_in,
                              void* d_out, int out_size, void* d_ws, size_t ws_size,
                              hipStream_t stream) {
    const float* x = (const float*)d_in[0];
    const float* L = (const float*)d_in[1];
    const float* b = (const float*)d_in[2];
    const float* c = (const float*)d_in[3];
    float* out = (float*)d_out;
    unsigned short* Ltf = (unsigned short*)d_ws;   // 512 KiB

    prep_lt<<<256, 256, 0, stream>>>(L, Ltf);
    psd_main<<<NBLOCKS, THREADS, 0, stream>>>(x, Ltf, b, c, out);
}